// Round 15
// baseline (433.435 us; speedup 1.0000x reference)
//
#include <hip/hip_runtime.h>
#include <hip/hip_bf16.h>
#include <hip/hip_cooperative_groups.h>

// Capsule dynamic routing — ONE cooperative dispatch, 512 blocks, per-batch
// spin barriers (NOT grid.sync: r11 measured ~70us per grid.sync).
// Empirical law from r3-r14: work inside a kernel runs at 3+ TB/s; every
// kbig-class dispatch boundary costs ~55us regardless of body. So: fuse all
// phases, sync only the 8 blocks of each batch via device-scope atomics.
// Per-wave math = r13 (proven absmax 0.0039): phase1 global frags, in-reg
// softmax, register c^T via shfl, phase2 global B-operand, hi/lo 3-term.

#define BB 64
#define NN 2048
#define DD 64
#define II 32
#define QB 8                  // blocks per batch
#define RPB 256               // rows per block (8 waves x 32)

typedef __attribute__((ext_vector_type(8)))  short bf16x8;
typedef __attribute__((ext_vector_type(16))) float f32x16;

__device__ __forceinline__ short f2bf(float f) {
    __hip_bfloat16 h = __float2bfloat16(f);
    return *reinterpret_cast<short*>(&h);
}
__device__ __forceinline__ float bf2f(short s) {
    __hip_bfloat16 h = *reinterpret_cast<__hip_bfloat16*>(&s);
    return __bfloat162float(h);
}

__device__ __forceinline__ void batch_barrier(int* cnt, int target) {
    __threadfence();                    // release: own stores -> coherence point
    __syncthreads();                    // whole block done + fenced
    if (threadIdx.x == 0) {
        __hip_atomic_fetch_add(cnt, 1, __ATOMIC_RELEASE, __HIP_MEMORY_SCOPE_AGENT);
        while (__hip_atomic_load(cnt, __ATOMIC_ACQUIRE, __HIP_MEMORY_SCOPE_AGENT) < target)
            __builtin_amdgcn_s_sleep(2);
    }
    __syncthreads();                    // acquire visible to all waves
}

// ---------------- cooperative kernel: 512 blocks x 512 threads ----------------
__global__ __launch_bounds__(512) void kco(const float* __restrict__ u,
                                           const float* __restrict__ W,
                                           float* __restrict__ out,
                                           int* __restrict__ cnt,
                                           float* __restrict__ spart,
                                           float* __restrict__ tglob) {
    int blk = blockIdx.x;
    int b = blk >> 3, q = blk & 7;      // batch, eighth (256 rows)
    int tid = threadIdx.x;
    int wv = tid >> 6;                  // wave 0..7, owns 32 rows
    int l = tid & 63, h = l >> 5, ln = l & 31;
    int ii = tid >> 4, jj0 = tid & 15;  // epilogue mapping

    __shared__ float tlds[II][65];      // 8.3 KB t reduce
    __shared__ float wlds[II][72];      // 9.2 KB w~ (pad 72)
    __shared__ float4 red[32][16];      // 8 KB phase-A reduce
    __shared__ float ssum[DD];
    __shared__ float osh[II][16];

    const float* ubase = u + (size_t)b * NN * DD;
    int rbase = q * RPB;                // this block's 256 rows

    // ---- phase A: partial s over this block's rows -> spart[blk] ----
    {
        int rr = tid >> 4, cg = tid & 15;
        const float4* up = reinterpret_cast<const float4*>(
            ubase + (size_t)rbase * DD) + cg;
        float4 a = {0.f, 0.f, 0.f, 0.f};
        #pragma unroll
        for (int m = 0; m < 8; ++m) {
            float4 v = up[(size_t)(rr + 32 * m) * 16];
            a.x += v.x; a.y += v.y; a.z += v.z; a.w += v.w;
        }
        red[rr][cg] = a;
    }
    for (int k = tid; k < II * 65; k += 512) (&tlds[0][0])[k] = 0.f;
    __syncthreads();
    if (tid < 16) {
        float4 s = red[0][tid];
        #pragma unroll
        for (int r = 1; r < 32; ++r) {
            s.x += red[r][tid].x; s.y += red[r][tid].y;
            s.z += red[r][tid].z; s.w += red[r][tid].w;
        }
        reinterpret_cast<float4*>(spart + (size_t)blk * DD)[tid] = s;
    }
    batch_barrier(&cnt[b * 4 + 0], QB);

    // ---- phase B (redundant x8): s total, o0, l2norm, w~ ----
    if (tid < DD) {
        float a = 0.f;
        #pragma unroll
        for (int q2 = 0; q2 < QB; ++q2) a += spart[(size_t)(b * QB + q2) * DD + tid];
        ssum[tid] = a;
    }
    __syncthreads();
    {
        float o = 0.f;
        #pragma unroll 8
        for (int d = 0; d < DD; ++d) o += ssum[d] * W[d * 512 + ii * 16 + jj0];
        o *= (1.0f / 32.0f);
        float ss = o * o;
        #pragma unroll
        for (int off = 8; off >= 1; off >>= 1) ss += __shfl_xor(ss, off, 16);
        osh[ii][jj0] = o / sqrtf(fmaxf(ss, 1e-12f));
    }
    __syncthreads();
    #pragma unroll
    for (int k = 0; k < 4; ++k) {
        int d = jj0 + 16 * k;
        float acc = 0.f;
        #pragma unroll
        for (int j2 = 0; j2 < 16; ++j2)
            acc += W[d * 512 + ii * 16 + j2] * osh[ii][j2];
        wlds[ii][d] = acc;
    }
    __syncthreads();

    // ---- routing iterations ----
    for (int it = 0; it < 2; ++it) {
        int n0 = rbase + wv * 32;       // this wave's 32 rows

        // phase 1: C1[n][i] = sum_d u[n][d]*w~[i][d]; A=u rows, B=w~^T (LDS)
        f32x16 S;
        #pragma unroll
        for (int r = 0; r < 16; ++r) S[r] = 0.f;
        #pragma unroll
        for (int kt = 0; kt < 4; ++kt) {
            int d0 = kt * 16 + h * 8;
            const float4* pa = reinterpret_cast<const float4*>(
                ubase + (size_t)(n0 + ln) * DD + d0);
            const float4* pb = reinterpret_cast<const float4*>(&wlds[ln][d0]);
            float4 a0 = pa[0], a1 = pa[1];
            float4 b0 = pb[0], b1 = pb[1];
            bf16x8 A, Bv;
            A[0]=f2bf(a0.x); A[1]=f2bf(a0.y); A[2]=f2bf(a0.z); A[3]=f2bf(a0.w);
            A[4]=f2bf(a1.x); A[5]=f2bf(a1.y); A[6]=f2bf(a1.z); A[7]=f2bf(a1.w);
            Bv[0]=f2bf(b0.x); Bv[1]=f2bf(b0.y); Bv[2]=f2bf(b0.z); Bv[3]=f2bf(b0.w);
            Bv[4]=f2bf(b1.x); Bv[5]=f2bf(b1.y); Bv[6]=f2bf(b1.z); Bv[7]=f2bf(b1.w);
            S = __builtin_amdgcn_mfma_f32_32x32x16_bf16(A, Bv, S, 0, 0, 0);
        }

        // softmax over i: reduce across the 32-lane group (offsets 1..16)
        float c[16];
        #pragma unroll
        for (int r = 0; r < 16; ++r) {
            float m = S[r];
            #pragma unroll
            for (int off = 1; off <= 16; off <<= 1) m = fmaxf(m, __shfl_xor(m, off));
            float e = __expf(S[r] - m);
            float s = e;
            #pragma unroll
            for (int off = 1; off <= 16; off <<= 1) s += __shfl_xor(s, off);
            c[r] = e / s;
        }

        // phase 2: C2[i][d] += sum_n c[n][i]*u[n][d]; A=c^T from regs
        f32x16 G0, G1;
        #pragma unroll
        for (int r = 0; r < 16; ++r) { G0[r] = 0.f; G1[r] = 0.f; }
        #pragma unroll
        for (int t2 = 0; t2 < 2; ++t2) {
            float pc[8];
            #pragma unroll
            for (int qq = 0; qq < 8; ++qq) pc[qq] = __shfl_xor(c[8 * t2 + qq], 32);
            bf16x8 Ah, Al;
            #pragma unroll
            for (int j = 0; j < 8; ++j) {
                float av = ((j >> 2) == h) ? c[8 * t2 + j] : pc[j ^ 4];
                short hi = f2bf(av);
                Ah[j] = hi;
                Al[j] = f2bf(av - bf2f(hi));
            }
            #pragma unroll
            for (int Nt = 0; Nt < 2; ++Nt) {
                bf16x8 Bh, Bl;
                #pragma unroll
                for (int j = 0; j < 8; ++j) {
                    int n = t2 * 16 + h * 8 + j;
                    float uv = ubase[(size_t)(n0 + n) * DD + Nt * 32 + ln];
                    short hi = f2bf(uv);
                    Bh[j] = hi;
                    Bl[j] = f2bf(uv - bf2f(hi));
                }
                if (Nt == 0) {
                    G0 = __builtin_amdgcn_mfma_f32_32x32x16_bf16(Ah, Bh, G0, 0, 0, 0);
                    G0 = __builtin_amdgcn_mfma_f32_32x32x16_bf16(Al, Bh, G0, 0, 0, 0);
                    G0 = __builtin_amdgcn_mfma_f32_32x32x16_bf16(Ah, Bl, G0, 0, 0, 0);
                } else {
                    G1 = __builtin_amdgcn_mfma_f32_32x32x16_bf16(Ah, Bh, G1, 0, 0, 0);
                    G1 = __builtin_amdgcn_mfma_f32_32x32x16_bf16(Al, Bh, G1, 0, 0, 0);
                    G1 = __builtin_amdgcn_mfma_f32_32x32x16_bf16(Ah, Bl, G1, 0, 0, 0);
                }
            }
        }

        // cross-wave LDS reduce -> tglob[blk]
        __syncthreads();                // tlds zeros / reuse ready
        #pragma unroll
        for (int r = 0; r < 16; ++r) {
            int irow = (r & 3) + 8 * (r >> 2) + 4 * h;
            atomicAdd(&tlds[irow][ln],      G0[r]);
            atomicAdd(&tlds[irow][32 + ln], G1[r]);
        }
        __syncthreads();
        {
            float* dst = tglob + (size_t)blk * (II * DD);
            for (int k = tid; k < II * DD; k += 512)
                dst[k] = tlds[k >> 6][k & 63];
        }
        batch_barrier(&cnt[b * 4 + 1 + it], QB);

        // redundant t total into tlds
        for (int k = tid; k < II * DD; k += 512) {
            float a = 0.f;
            #pragma unroll
            for (int q2 = 0; q2 < QB; ++q2)
                a += tglob[(size_t)(b * QB + q2) * (II * DD) + k];
            tlds[k >> 6][k & 63] = a;
        }
        __syncthreads();

        // epilogue
        float o = 0.f;
        #pragma unroll 8
        for (int d = 0; d < DD; ++d) o += tlds[ii][d] * W[d * 512 + ii * 16 + jj0];
        float ss = o * o;
        #pragma unroll
        for (int off = 8; off >= 1; off >>= 1) ss += __shfl_xor(ss, off, 16);

        if (it == 0) {
            float ov = o / sqrtf(fmaxf(ss, 1e-12f));     // tf l2_normalize
            __syncthreads();
            osh[ii][jj0] = ov;
            __syncthreads();
            #pragma unroll
            for (int k = 0; k < 4; ++k) {
                int d = jj0 + 16 * k;
                float acc = 0.f;
                #pragma unroll
                for (int j2 = 0; j2 < 16; ++j2)
                    acc += W[d * 512 + ii * 16 + j2] * osh[ii][j2];
                wlds[ii][d] = acc;
            }
            for (int k = tid; k < II * 65; k += 512) (&tlds[0][0])[k] = 0.f;
            __syncthreads();
        } else if (q == 0) {
            float s2 = ss + 1e-7f;                       // K.epsilon
            float scale = sqrtf(s2) / (0.5f + s2);       // squash
            out[(size_t)b * 512 + tid] = scale * o;
        }
    }
}

// ---------------- fallback: r10's proven single-dispatch kernel (100.8us) ----
__global__ __launch_bounds__(512) void kall(const float* __restrict__ u,
                                            const float* __restrict__ W,
                                            float* __restrict__ out) {
    int b = blockIdx.x;
    int tid = threadIdx.x;
    int wv = tid >> 6;
    int l = tid & 63, h = l >> 5, ln = l & 31;
    int ii = tid >> 4, jj0 = tid & 15;

    __shared__ unsigned short ush[8][2048];
    __shared__ unsigned short usl[8][2048];
    __shared__ float cslab[8][II * 33];
    __shared__ float tlds[II][65];
    __shared__ float wlds[II][68];
    __shared__ float slds[8][DD];
    __shared__ float ssum[DD];
    __shared__ float osh[II][16];

    const float* ubase = u + (size_t)b * NN * DD;

    {
        const float4* up = reinterpret_cast<const float4*>(ubase + (size_t)wv * 256 * DD);
        int r0 = l >> 4, c4 = l & 15;
        float4 a0 = {0.f, 0.f, 0.f, 0.f};
        #pragma unroll 8
        for (int s = 0; s < 64; ++s) {
            float4 v = up[(s * 4 + r0) * 16 + c4];
            a0.x += v.x; a0.y += v.y; a0.z += v.z; a0.w += v.w;
        }
        #pragma unroll
        for (int off = 16; off <= 32; off <<= 1) {
            a0.x += __shfl_xor(a0.x, off);
            a0.y += __shfl_xor(a0.y, off);
            a0.z += __shfl_xor(a0.z, off);
            a0.w += __shfl_xor(a0.w, off);
        }
        if (l < 16) *reinterpret_cast<float4*>(&slds[wv][l * 4]) = a0;
    }
    for (int k = tid; k < II * 65; k += 512) (&tlds[0][0])[k] = 0.f;
    __syncthreads();

    if (tid < DD) {
        float a = 0.f;
        #pragma unroll
        for (int wq = 0; wq < 8; ++wq) a += slds[wq][tid];
        ssum[tid] = a;
    }
    __syncthreads();
    {
        float o = 0.f;
        #pragma unroll 8
        for (int d = 0; d < DD; ++d) o += ssum[d] * W[d * 512 + ii * 16 + jj0];
        o *= (1.0f / 32.0f);
        float ss = o * o;
        #pragma unroll
        for (int off = 8; off >= 1; off >>= 1) ss += __shfl_xor(ss, off, 16);
        osh[ii][jj0] = o / sqrtf(fmaxf(ss, 1e-12f));
    }
    __syncthreads();
    #pragma unroll
    for (int k = 0; k < 4; ++k) {
        int d = jj0 + 16 * k;
        float acc = 0.f;
        #pragma unroll
        for (int j2 = 0; j2 < 16; ++j2)
            acc += W[d * 512 + ii * 16 + j2] * osh[ii][j2];
        wlds[ii][d] = acc;
    }
    __syncthreads();

    for (int it = 0; it < 2; ++it) {
        bf16x8 Aw[4];
        #pragma unroll
        for (int kt = 0; kt < 4; ++kt) {
            const float* p = &wlds[ln][kt * 16 + h * 8];
            #pragma unroll
            for (int e2 = 0; e2 < 8; ++e2) Aw[kt][e2] = f2bf(p[e2]);
        }
        f32x16 G0, G1;
        #pragma unroll
        for (int r = 0; r < 16; ++r) { G0[r] = 0.f; G1[r] = 0.f; }

        for (int tt = 0; tt < 8; ++tt) {
            int n0 = wv * 256 + tt * 32;
            bf16x8 Bh[4], Bl[4];
            #pragma unroll
            for (int kt = 0; kt < 4; ++kt) {
                const float4* p = reinterpret_cast<const float4*>(
                    ubase + (size_t)(n0 + ln) * DD + kt * 16 + h * 8);
                float4 v0 = p[0], v1 = p[1];
                float vf[8] = {v0.x, v0.y, v0.z, v0.w, v1.x, v1.y, v1.z, v1.w};
                #pragma unroll
                for (int e2 = 0; e2 < 8; ++e2) {
                    short hi = f2bf(vf[e2]);
                    Bh[kt][e2] = hi;
                    Bl[kt][e2] = f2bf(vf[e2] - bf2f(hi));
                }
                int d0 = kt * 16 + h * 8;
                int idx = ln * 64 + (d0 ^ ((ln & 7) << 3));
                *reinterpret_cast<bf16x8*>(&ush[wv][idx]) = Bh[kt];
                *reinterpret_cast<bf16x8*>(&usl[wv][idx]) = Bl[kt];
            }
            f32x16 S;
            #pragma unroll
            for (int r = 0; r < 16; ++r) S[r] = 0.f;
            #pragma unroll
            for (int kt = 0; kt < 4; ++kt)
                S = __builtin_amdgcn_mfma_f32_32x32x16_bf16(Aw[kt], Bh[kt], S, 0, 0, 0);
            float m = S[0];
            #pragma unroll
            for (int r = 1; r < 16; ++r) m = fmaxf(m, S[r]);
            m = fmaxf(m, __shfl_xor(m, 32));
            float sum = 0.f, e[16];
            #pragma unroll
            for (int r = 0; r < 16; ++r) { e[r] = __expf(S[r] - m); sum += e[r]; }
            sum += __shfl_xor(sum, 32);
            float inv = 1.f / sum;
            #pragma unroll
            for (int r = 0; r < 16; ++r) {
                int irow = (r & 3) + 8 * (r >> 2) + 4 * h;
                cslab[wv][ln * 33 + irow] = e[r] * inv;
            }
            #pragma unroll
            for (int t2 = 0; t2 < 2; ++t2) {
                bf16x8 Ah, Al;
                #pragma unroll
                for (int qq = 0; qq < 8; ++qq) {
                    float cv = cslab[wv][(t2 * 16 + h * 8 + qq) * 33 + ln];
                    short hi = f2bf(cv);
                    Ah[qq] = hi;
                    Al[qq] = f2bf(cv - bf2f(hi));
                }
                #pragma unroll
                for (int Nt = 0; Nt < 2; ++Nt) {
                    bf16x8 B2h, B2l;
                    #pragma unroll
                    for (int qq = 0; qq < 8; ++qq) {
                        int row = t2 * 16 + h * 8 + qq;
                        int idx = row * 64 + ((Nt * 32 + ln) ^ ((row & 7) << 3));
                        B2h[qq] = (short)ush[wv][idx];
                        B2l[qq] = (short)usl[wv][idx];
                    }
                    if (Nt == 0) {
                        G0 = __builtin_amdgcn_mfma_f32_32x32x16_bf16(Ah, B2h, G0, 0, 0, 0);
                        G0 = __builtin_amdgcn_mfma_f32_32x32x16_bf16(Al, B2h, G0, 0, 0, 0);
                        G0 = __builtin_amdgcn_mfma_f32_32x32x16_bf16(Ah, B2l, G0, 0, 0, 0);
                    } else {
                        G1 = __builtin_amdgcn_mfma_f32_32x32x16_bf16(Ah, B2h, G1, 0, 0, 0);
                        G1 = __builtin_amdgcn_mfma_f32_32x32x16_bf16(Al, B2h, G1, 0, 0, 0);
                        G1 = __builtin_amdgcn_mfma_f32_32x32x16_bf16(Ah, B2l, G1, 0, 0, 0);
                    }
                }
            }
        }
        #pragma unroll
        for (int r = 0; r < 16; ++r) {
            int irow = (r & 3) + 8 * (r >> 2) + 4 * h;
            atomicAdd(&tlds[irow][ln],      G0[r]);
            atomicAdd(&tlds[irow][32 + ln], G1[r]);
        }
        __syncthreads();

        float o = 0.f;
        #pragma unroll 8
        for (int d = 0; d < DD; ++d) o += tlds[ii][d] * W[d * 512 + ii * 16 + jj0];
        float ss = o * o;
        #pragma unroll
        for (int off = 8; off >= 1; off >>= 1) ss += __shfl_xor(ss, off, 16);

        if (it == 0) {
            float ov = o / sqrtf(fmaxf(ss, 1e-12f));
            __syncthreads();
            osh[ii][jj0] = ov;
            __syncthreads();
            #pragma unroll
            for (int k = 0; k < 4; ++k) {
                int d = jj0 + 16 * k;
                float acc = 0.f;
                #pragma unroll
                for (int j2 = 0; j2 < 16; ++j2)
                    acc += W[d * 512 + ii * 16 + j2] * osh[ii][j2];
                wlds[ii][d] = acc;
            }
            for (int k = tid; k < II * 65; k += 512) (&tlds[0][0])[k] = 0.f;
            __syncthreads();
        } else {
            float s2 = ss + 1e-7f;
            float scale = sqrtf(s2) / (0.5f + s2);
            out[(size_t)b * 512 + tid] = scale * o;
        }
    }
}

extern "C" void kernel_launch(void* const* d_in, const int* in_sizes, int n_in,
                              void* d_out, int out_size, void* d_ws, size_t ws_size,
                              hipStream_t stream) {
    const float* u = (const float*)d_in[0];     // (64, 2048, 64)
    const float* W = (const float*)d_in[1];     // (1, 64, 512)
    float* out = (float*)d_out;                 // (64, 32, 16)
    float* ws = (float*)d_ws;

    int*   cnt   = (int*)ws;                    // 256 ints (use 1024 floats pad)
    float* spart = ws + 1024;                   // 512*64 floats   (128 KB)
    float* tglob = ws + 1024 + 512 * DD;        // 512*2048 floats (4 MB)
    // total ~4.3 MB < 9.96 MB proven available.

    hipMemsetAsync(cnt, 0, 256 * sizeof(int), stream);  // barrier counters

    void* args[] = {(void*)&u, (void*)&W, (void*)&out,
                    (void*)&cnt, (void*)&spart, (void*)&tglob};
    hipError_t e = hipLaunchCooperativeKernel((const void*)kco, dim3(512), dim3(512),
                                              args, 0, stream);
    if (e != hipSuccess) {
        // deterministic per-environment fallback: r10's proven kernel
        kall<<<BB, 512, 0, stream>>>(u, W, out);
    }
}

// Round 16
// 240.390 us; speedup vs baseline: 1.8030x; 1.8030x over previous
//
#include <hip/hip_runtime.h>
#include <hip/hip_bf16.h>

// Capsule dynamic routing — ONE dispatch, 64 blocks x 1024 threads (16 waves).
// r15: all cross-block sync is catastrophic (~100us/barrier). r10 (64x512,
// one dispatch) = 100.8us best; its 110us kernel = 2 x ~55us per routing
// iteration, latency-bound at 2 waves/SIMD. This round doubles intra-block
// wave parallelism (4/SIMD) and halves per-wave serial work (128 rows/wave).
// Wave tile math = r13 (proven absmax 0.0039): register softmax + register
// c^T, global operands, hi/lo 3-term phase 2. LDS 19KB.

#define BB 64
#define NN 2048
#define DD 64
#define II 32
#define WPB 16                // waves per block
#define TPB 1024

typedef __attribute__((ext_vector_type(8)))  short bf16x8;
typedef __attribute__((ext_vector_type(16))) float f32x16;

__device__ __forceinline__ short f2bf(float f) {
    __hip_bfloat16 h = __float2bfloat16(f);
    return *reinterpret_cast<short*>(&h);
}
__device__ __forceinline__ float bf2f(short s) {
    __hip_bfloat16 h = *reinterpret_cast<__hip_bfloat16*>(&s);
    return __bfloat162float(h);
}

__global__ __launch_bounds__(TPB) void kone(const float* __restrict__ u,
                                            const float* __restrict__ W,
                                            float* __restrict__ out) {
    int b = blockIdx.x;
    int tid = threadIdx.x;
    int wv = tid >> 6;                  // wave 0..15, owns 128 rows
    int l = tid & 63, h = l >> 5, ln = l & 31;
    int ii = (tid >> 4) & 31, jj0 = tid & 15;   // epilogue map (tid<512)

    __shared__ float tlds[II][65];      // 8.3 KB t-reduce (also phase-A scratch)
    __shared__ float wlds[II][68];      // 8.7 KB w~ (b128 conflict-free pad)
    __shared__ float osh[II][16];       // 2 KB
    __shared__ float ssum[DD];          // 256 B

    const float* ubase = u + (size_t)b * NN * DD;

    // ---- phase A: s[d] = sum_n u[n][d]; wave wv sums its 128 rows ----
    {
        const float4* up = reinterpret_cast<const float4*>(
            ubase + (size_t)wv * 128 * DD);
        int r0 = l >> 4, c4 = l & 15;
        float4 a0 = {0.f, 0.f, 0.f, 0.f};
        #pragma unroll 8
        for (int s2 = 0; s2 < 32; ++s2) {
            float4 v = up[(s2 * 4 + r0) * 16 + c4];
            a0.x += v.x; a0.y += v.y; a0.z += v.z; a0.w += v.w;
        }
        #pragma unroll
        for (int off = 16; off <= 32; off <<= 1) {
            a0.x += __shfl_xor(a0.x, off);
            a0.y += __shfl_xor(a0.y, off);
            a0.z += __shfl_xor(a0.z, off);
            a0.w += __shfl_xor(a0.w, off);
        }
        if (l < 16)
            reinterpret_cast<float4*>(&tlds[0][0])[wv * 16 + l] = a0;  // scratch
    }
    __syncthreads();
    if (tid < DD) {
        const float* slds = &tlds[0][0];
        float a = 0.f;
        #pragma unroll
        for (int wq = 0; wq < WPB; ++wq) a += slds[wq * 64 + tid];
        ssum[tid] = a;
    }
    __syncthreads();

    // ---- phase B: o0 = (1/32) s @ W, l2norm -> osh (tid<512) ----
    if (tid < 512) {
        float o = 0.f;
        #pragma unroll 8
        for (int d = 0; d < DD; ++d) o += ssum[d] * W[d * 512 + ii * 16 + jj0];
        o *= (1.0f / 32.0f);
        float ss = o * o;
        #pragma unroll
        for (int off = 8; off >= 1; off >>= 1) ss += __shfl_xor(ss, off, 16);
        osh[ii][jj0] = o / sqrtf(fmaxf(ss, 1e-12f));
    }
    __syncthreads();
    if (tid < 512) {
        #pragma unroll
        for (int k = 0; k < 4; ++k) {
            int d = jj0 + 16 * k;
            float acc = 0.f;
            #pragma unroll
            for (int j2 = 0; j2 < 16; ++j2)
                acc += W[d * 512 + ii * 16 + j2] * osh[ii][j2];
            wlds[ii][d] = acc;
        }
    } else {
        for (int k = tid - 512; k < II * 65; k += 512) (&tlds[0][0])[k] = 0.f;
    }
    __syncthreads();

    // ---- routing iterations ----
    for (int it = 0; it < 2; ++it) {
        f32x16 G0, G1;
        #pragma unroll
        for (int r = 0; r < 16; ++r) { G0[r] = 0.f; G1[r] = 0.f; }

        #pragma unroll
        for (int tt = 0; tt < 4; ++tt) {
            int n0 = wv * 128 + tt * 32;            // this wave's tile rows

            // phase 1: C1[n][i] = sum_d u[n][d]*w~[i][d]; A=u rows, B=w~^T
            f32x16 S;
            #pragma unroll
            for (int r = 0; r < 16; ++r) S[r] = 0.f;
            #pragma unroll
            for (int kt = 0; kt < 4; ++kt) {
                int d0 = kt * 16 + h * 8;
                const float4* pa = reinterpret_cast<const float4*>(
                    ubase + (size_t)(n0 + ln) * DD + d0);
                const float4* pb = reinterpret_cast<const float4*>(&wlds[ln][d0]);
                float4 a0 = pa[0], a1 = pa[1];
                float4 b0 = pb[0], b1 = pb[1];
                bf16x8 A, Bv;
                A[0]=f2bf(a0.x); A[1]=f2bf(a0.y); A[2]=f2bf(a0.z); A[3]=f2bf(a0.w);
                A[4]=f2bf(a1.x); A[5]=f2bf(a1.y); A[6]=f2bf(a1.z); A[7]=f2bf(a1.w);
                Bv[0]=f2bf(b0.x); Bv[1]=f2bf(b0.y); Bv[2]=f2bf(b0.z); Bv[3]=f2bf(b0.w);
                Bv[4]=f2bf(b1.x); Bv[5]=f2bf(b1.y); Bv[6]=f2bf(b1.z); Bv[7]=f2bf(b1.w);
                S = __builtin_amdgcn_mfma_f32_32x32x16_bf16(A, Bv, S, 0, 0, 0);
            }

            // softmax over i: butterfly within the 32-lane group
            float c[16];
            #pragma unroll
            for (int r = 0; r < 16; ++r) {
                float m = S[r];
                #pragma unroll
                for (int off = 1; off <= 16; off <<= 1)
                    m = fmaxf(m, __shfl_xor(m, off));
                float e = __expf(S[r] - m);
                float s = e;
                #pragma unroll
                for (int off = 1; off <= 16; off <<= 1)
                    s += __shfl_xor(s, off);
                c[r] = e / s;
            }

            // phase 2: G += mfma(c^T, u cols); c^T assembled in registers
            #pragma unroll
            for (int t2 = 0; t2 < 2; ++t2) {
                float pc[8];
                #pragma unroll
                for (int qq = 0; qq < 8; ++qq) pc[qq] = __shfl_xor(c[8 * t2 + qq], 32);
                bf16x8 Ah, Al;
                #pragma unroll
                for (int j = 0; j < 8; ++j) {
                    float av = ((j >> 2) == h) ? c[8 * t2 + j] : pc[j ^ 4];
                    short hi = f2bf(av);
                    Ah[j] = hi;
                    Al[j] = f2bf(av - bf2f(hi));
                }
                #pragma unroll
                for (int Nt = 0; Nt < 2; ++Nt) {
                    bf16x8 Bh, Bl;
                    #pragma unroll
                    for (int j = 0; j < 8; ++j) {
                        int n = t2 * 16 + h * 8 + j;
                        float uv = ubase[(size_t)(n0 + n) * DD + Nt * 32 + ln];
                        short hi = f2bf(uv);
                        Bh[j] = hi;
                        Bl[j] = f2bf(uv - bf2f(hi));
                    }
                    if (Nt == 0) {
                        G0 = __builtin_amdgcn_mfma_f32_32x32x16_bf16(Ah, Bh, G0, 0, 0, 0);
                        G0 = __builtin_amdgcn_mfma_f32_32x32x16_bf16(Al, Bh, G0, 0, 0, 0);
                        G0 = __builtin_amdgcn_mfma_f32_32x32x16_bf16(Ah, Bl, G0, 0, 0, 0);
                    } else {
                        G1 = __builtin_amdgcn_mfma_f32_32x32x16_bf16(Ah, Bh, G1, 0, 0, 0);
                        G1 = __builtin_amdgcn_mfma_f32_32x32x16_bf16(Al, Bh, G1, 0, 0, 0);
                        G1 = __builtin_amdgcn_mfma_f32_32x32x16_bf16(Ah, Bl, G1, 0, 0, 0);
                    }
                }
            }
        }

        // cross-wave LDS reduce (tlds pre-zeroed)
        #pragma unroll
        for (int r = 0; r < 16; ++r) {
            int irow = (r & 3) + 8 * (r >> 2) + 4 * h;
            atomicAdd(&tlds[irow][ln],      G0[r]);
            atomicAdd(&tlds[irow][32 + ln], G1[r]);
        }
        __syncthreads();

        // epilogue: o = t @ W_i (tid<512)
        float o = 0.f, ss = 0.f;
        if (tid < 512) {
            #pragma unroll 8
            for (int d = 0; d < DD; ++d) o += tlds[ii][d] * W[d * 512 + ii * 16 + jj0];
            ss = o * o;
            #pragma unroll
            for (int off = 8; off >= 1; off >>= 1) ss += __shfl_xor(ss, off, 16);
        }
        __syncthreads();                // all tlds reads done before re-zero

        if (it == 0) {
            if (tid < 512)
                osh[ii][jj0] = o / sqrtf(fmaxf(ss, 1e-12f));    // l2norm
            __syncthreads();
            if (tid < 512) {            // rebuild w~
                #pragma unroll
                for (int k = 0; k < 4; ++k) {
                    int d = jj0 + 16 * k;
                    float acc = 0.f;
                    #pragma unroll
                    for (int j2 = 0; j2 < 16; ++j2)
                        acc += W[d * 512 + ii * 16 + j2] * osh[ii][j2];
                    wlds[ii][d] = acc;
                }
            } else {                    // re-zero tlds in parallel
                for (int k = tid - 512; k < II * 65; k += 512)
                    (&tlds[0][0])[k] = 0.f;
            }
            __syncthreads();
        } else if (tid < 512) {
            float s2 = ss + 1e-7f;                    // K.epsilon
            float scale = sqrtf(s2) / (0.5f + s2);    // squash
            out[(size_t)b * 512 + tid] = scale * o;
        }
    }
}

extern "C" void kernel_launch(void* const* d_in, const int* in_sizes, int n_in,
                              void* d_out, int out_size, void* d_ws, size_t ws_size,
                              hipStream_t stream) {
    const float* u = (const float*)d_in[0];     // (64, 2048, 64)
    const float* W = (const float*)d_in[1];     // (1, 64, 512)
    float* out = (float*)d_out;                 // (64, 32, 16)
    (void)d_ws; (void)ws_size;

    kone<<<BB, TPB, 0, stream>>>(u, W, out);    // ONE dispatch
}

// Round 17
// 140.269 us; speedup vs baseline: 3.0900x; 1.7138x over previous
//
#include <hip/hip_runtime.h>
#include <hip/hip_bf16.h>

// Capsule dynamic routing — TWO dispatches:
//   ksum (wide, 2048 wg): spart = per-64-row sums of u  (uses all CUs, fast)
//   kf   (64 x 512):      everything else, software-pipelined tile loop.
// r16 post-mortem: 64-block kernels move u at ~350 GB/s (latency-bound);
// global phase-2 reads tripled FETCH and thrashed L2. This round: phase A
// extracted to the wide kernel; kf keeps r10's LDS-staged phase 2 (low
// FETCH) and adds explicit 1-tile-ahead register prefetch so tile t+1's
// 8 float4 loads overlap tile t's cvt/MFMA/softmax (~600cyc hidden).
// Tile math verbatim r10/r13 (proven absmax 0.0039).

#define BB 64
#define NN 2048
#define DD 64
#define II 32

typedef __attribute__((ext_vector_type(8)))  short bf16x8;
typedef __attribute__((ext_vector_type(16))) float f32x16;

__device__ __forceinline__ short f2bf(float f) {
    __hip_bfloat16 h = __float2bfloat16(f);
    return *reinterpret_cast<short*>(&h);
}
__device__ __forceinline__ float bf2f(short s) {
    __hip_bfloat16 h = *reinterpret_cast<__hip_bfloat16*>(&s);
    return __bfloat162float(h);
}

// ---------------- wide kernel: spart[cb][b][d] = sum of 64 rows ----------------
__global__ __launch_bounds__(256) void ksum(const float* __restrict__ u,
                                            float* __restrict__ spart) {
    int b = blockIdx.y, cb = blockIdx.x;        // cb: 0..31, 64 rows each
    int tid = threadIdx.x, cg = tid & 15, rr = tid >> 4;
    const float4* up = reinterpret_cast<const float4*>(
        u + ((size_t)b * NN + (size_t)cb * 64 + rr) * DD) + cg;
    float4 a = {0.f, 0.f, 0.f, 0.f};
    #pragma unroll
    for (int k = 0; k < 4; ++k) {
        float4 v = up[(size_t)k * 16 * (DD / 4)];
        a.x += v.x; a.y += v.y; a.z += v.z; a.w += v.w;
    }
    __shared__ float4 red[16][16];
    red[rr][cg] = a;
    __syncthreads();
    if (rr == 0) {
        float4 s = red[0][cg];
        #pragma unroll
        for (int r = 1; r < 16; ++r) {
            s.x += red[r][cg].x; s.y += red[r][cg].y;
            s.z += red[r][cg].z; s.w += red[r][cg].w;
        }
        reinterpret_cast<float4*>(spart + ((size_t)cb * BB + b) * DD)[cg] = s;
    }
}

// ---------------- fused kernel: 64 blocks x 512 threads ----------------
__global__ __launch_bounds__(512) void kf(const float* __restrict__ u,
                                          const float* __restrict__ W,
                                          const float* __restrict__ spart,
                                          float* __restrict__ out) {
    int b = blockIdx.x;
    int tid = threadIdx.x;
    int wv = tid >> 6;                  // wave 0..7, owns 256 rows
    int l = tid & 63, h = l >> 5, ln = l & 31;
    int ii = tid >> 4, jj0 = tid & 15;

    __shared__ unsigned short ush[8][2048];   // per-wave 32-row u tile, bf16 hi
    __shared__ unsigned short usl[8][2048];   // lo plane
    __shared__ float cslab[8][II * 33];
    __shared__ float tlds[II][65];
    __shared__ float wlds[II][68];
    __shared__ float ssum[DD];
    __shared__ float osh[II][16];

    const float* ubase = u + (size_t)b * NN * DD;

    // ---- phase B: s total from spart, o0, l2norm, w~ ----
    if (tid < DD) {
        float a = 0.f;
        #pragma unroll
        for (int cb = 0; cb < 32; ++cb)
            a += spart[((size_t)cb * BB + b) * DD + tid];
        ssum[tid] = a;
    }
    for (int k = tid; k < II * 65; k += 512) (&tlds[0][0])[k] = 0.f;
    __syncthreads();
    {
        float o = 0.f;
        #pragma unroll 8
        for (int d = 0; d < DD; ++d) o += ssum[d] * W[d * 512 + ii * 16 + jj0];
        o *= (1.0f / 32.0f);
        float ss = o * o;
        #pragma unroll
        for (int off = 8; off >= 1; off >>= 1) ss += __shfl_xor(ss, off, 16);
        osh[ii][jj0] = o / sqrtf(fmaxf(ss, 1e-12f));
    }
    __syncthreads();
    #pragma unroll
    for (int k = 0; k < 4; ++k) {
        int d = jj0 + 16 * k;
        float acc = 0.f;
        #pragma unroll
        for (int j2 = 0; j2 < 16; ++j2)
            acc += W[d * 512 + ii * 16 + j2] * osh[ii][j2];
        wlds[ii][d] = acc;
    }
    __syncthreads();

    // ---- routing iterations ----
    for (int it = 0; it < 2; ++it) {
        bf16x8 Aw[4];
        #pragma unroll
        for (int kt = 0; kt < 4; ++kt) {
            const float* p = &wlds[ln][kt * 16 + h * 8];
            #pragma unroll
            for (int e2 = 0; e2 < 8; ++e2) Aw[kt][e2] = f2bf(p[e2]);
        }
        f32x16 G0, G1;
        #pragma unroll
        for (int r = 0; r < 16; ++r) { G0[r] = 0.f; G1[r] = 0.f; }

        // -- software-pipelined 8-tile loop: prefetch tile tt+1 during tile tt --
        float4 cur[8], nxt[8];
        {
            const float4* p = reinterpret_cast<const float4*>(
                ubase + (size_t)(wv * 256 + ln) * DD);
            #pragma unroll
            for (int kt = 0; kt < 4; ++kt) {
                cur[kt * 2 + 0] = p[kt * 4 + h * 2 + 0];
                cur[kt * 2 + 1] = p[kt * 4 + h * 2 + 1];
            }
        }
        #pragma unroll
        for (int tt = 0; tt < 8; ++tt) {
            if (tt < 7) {                       // issue next tile's loads NOW
                const float4* p = reinterpret_cast<const float4*>(
                    ubase + (size_t)(wv * 256 + (tt + 1) * 32 + ln) * DD);
                #pragma unroll
                for (int kt = 0; kt < 4; ++kt) {
                    nxt[kt * 2 + 0] = p[kt * 4 + h * 2 + 0];
                    nxt[kt * 2 + 1] = p[kt * 4 + h * 2 + 1];
                }
            }
            // cvt current tile -> Bh/Bl + per-wave swizzled LDS slabs
            bf16x8 Bh[4], Bl[4];
            #pragma unroll
            for (int kt = 0; kt < 4; ++kt) {
                float4 v0 = cur[kt * 2 + 0], v1 = cur[kt * 2 + 1];
                float vf[8] = {v0.x, v0.y, v0.z, v0.w, v1.x, v1.y, v1.z, v1.w};
                #pragma unroll
                for (int e2 = 0; e2 < 8; ++e2) {
                    short hi = f2bf(vf[e2]);
                    Bh[kt][e2] = hi;
                    Bl[kt][e2] = f2bf(vf[e2] - bf2f(hi));
                }
                int d0 = kt * 16 + h * 8;
                int idx = ln * 64 + (d0 ^ ((ln & 7) << 3));
                *reinterpret_cast<bf16x8*>(&ush[wv][idx]) = Bh[kt];
                *reinterpret_cast<bf16x8*>(&usl[wv][idx]) = Bl[kt];
            }
            // phase 1: logits C[i][n], col = ln
            f32x16 S;
            #pragma unroll
            for (int r = 0; r < 16; ++r) S[r] = 0.f;
            #pragma unroll
            for (int kt = 0; kt < 4; ++kt)
                S = __builtin_amdgcn_mfma_f32_32x32x16_bf16(Aw[kt], Bh[kt], S, 0, 0, 0);
            // softmax over i (16 lane-local + partner half via xor 32)
            float m = S[0];
            #pragma unroll
            for (int r = 1; r < 16; ++r) m = fmaxf(m, S[r]);
            m = fmaxf(m, __shfl_xor(m, 32));
            float sum = 0.f, e[16];
            #pragma unroll
            for (int r = 0; r < 16; ++r) { e[r] = __expf(S[r] - m); sum += e[r]; }
            sum += __shfl_xor(sum, 32);
            float inv = 1.f / sum;
            #pragma unroll
            for (int r = 0; r < 16; ++r) {
                int irow = (r & 3) + 8 * (r >> 2) + 4 * h;
                cslab[wv][ln * 33 + irow] = e[r] * inv;   // c[n=ln][i]
            }
            // phase 2: G += mfma(c^T, u) from per-wave LDS slabs
            #pragma unroll
            for (int t2 = 0; t2 < 2; ++t2) {
                bf16x8 Ah, Al;
                #pragma unroll
                for (int qq = 0; qq < 8; ++qq) {
                    float cv = cslab[wv][(t2 * 16 + h * 8 + qq) * 33 + ln];
                    short hi = f2bf(cv);
                    Ah[qq] = hi;
                    Al[qq] = f2bf(cv - bf2f(hi));
                }
                #pragma unroll
                for (int Nt = 0; Nt < 2; ++Nt) {
                    bf16x8 B2h, B2l;
                    #pragma unroll
                    for (int qq = 0; qq < 8; ++qq) {
                        int row = t2 * 16 + h * 8 + qq;
                        int idx = row * 64 + ((Nt * 32 + ln) ^ ((row & 7) << 3));
                        B2h[qq] = (short)ush[wv][idx];
                        B2l[qq] = (short)usl[wv][idx];
                    }
                    if (Nt == 0) {
                        G0 = __builtin_amdgcn_mfma_f32_32x32x16_bf16(Ah, B2h, G0, 0, 0, 0);
                        G0 = __builtin_amdgcn_mfma_f32_32x32x16_bf16(Al, B2h, G0, 0, 0, 0);
                        G0 = __builtin_amdgcn_mfma_f32_32x32x16_bf16(Ah, B2l, G0, 0, 0, 0);
                    } else {
                        G1 = __builtin_amdgcn_mfma_f32_32x32x16_bf16(Ah, B2h, G1, 0, 0, 0);
                        G1 = __builtin_amdgcn_mfma_f32_32x32x16_bf16(Al, B2h, G1, 0, 0, 0);
                        G1 = __builtin_amdgcn_mfma_f32_32x32x16_bf16(Ah, B2l, G1, 0, 0, 0);
                    }
                }
            }
            // rotate prefetch buffer (full unroll -> register rename, no moves)
            #pragma unroll
            for (int q = 0; q < 8; ++q) cur[q] = nxt[q];
        }

        // cross-wave LDS reduce
        #pragma unroll
        for (int r = 0; r < 16; ++r) {
            int irow = (r & 3) + 8 * (r >> 2) + 4 * h;
            atomicAdd(&tlds[irow][ln],      G0[r]);
            atomicAdd(&tlds[irow][32 + ln], G1[r]);
        }
        __syncthreads();

        // epilogue: o = t @ W_i, l2norm->w~ or squash->out
        float o = 0.f;
        #pragma unroll 8
        for (int d = 0; d < DD; ++d) o += tlds[ii][d] * W[d * 512 + ii * 16 + jj0];
        float ss = o * o;
        #pragma unroll
        for (int off = 8; off >= 1; off >>= 1) ss += __shfl_xor(ss, off, 16);

        if (it == 0) {
            float ov = o / sqrtf(fmaxf(ss, 1e-12f));     // tf l2_normalize
            __syncthreads();
            osh[ii][jj0] = ov;
            __syncthreads();
            #pragma unroll
            for (int k = 0; k < 4; ++k) {
                int d = jj0 + 16 * k;
                float acc = 0.f;
                #pragma unroll
                for (int j2 = 0; j2 < 16; ++j2)
                    acc += W[d * 512 + ii * 16 + j2] * osh[ii][j2];
                wlds[ii][d] = acc;
            }
            for (int k = tid; k < II * 65; k += 512) (&tlds[0][0])[k] = 0.f;
            __syncthreads();
        } else {
            float s2 = ss + 1e-7f;                       // K.epsilon
            float scale = sqrtf(s2) / (0.5f + s2);       // squash
            out[(size_t)b * 512 + tid] = scale * o;
        }
    }
}

extern "C" void kernel_launch(void* const* d_in, const int* in_sizes, int n_in,
                              void* d_out, int out_size, void* d_ws, size_t ws_size,
                              hipStream_t stream) {
    const float* u = (const float*)d_in[0];     // (64, 2048, 64)
    const float* W = (const float*)d_in[1];     // (1, 64, 512)
    float* out = (float*)d_out;                 // (64, 32, 16)
    float* ws = (float*)d_ws;

    float* spart = ws;                          // 131072 floats (512 KB)

    ksum<<<dim3(32, BB), 256, 0, stream>>>(u, spart);   // wide: all CUs
    kf<<<BB, 512, 0, stream>>>(u, W, spart, out);       // fused routing
}

// Round 18
// 100.581 us; speedup vs baseline: 4.3093x; 1.3946x over previous
//
#include <hip/hip_runtime.h>
#include <hip/hip_bf16.h>

// Capsule dynamic routing — TWO dispatches:
//   ksum (wide, 2048 wg): spart = per-64-row sums of u (all CUs, ~free)
//   kf   (64 x 512):      fused routing, MINIMAL ops.
// r17 post-mortem: prefetch regressed (VGPR 128); replays speed up
// monotonically -> clock-ramp explains the ~55us fixed cost; only lever is
// less serial work. r18: drop BOTH lo-planes (phase2 hi-only bf16):
// 12->4 MFMA/tile, -16KB LDS, ~30% less cvt VALU. Predicted absmax ~6-10e-3
// (phase1-bf16 contributed ~2e-3 on top of 1.95e-3 fp32 floor; phase2 adds
// similar). Structure otherwise = proven r10.

#define BB 64
#define NN 2048
#define DD 64
#define II 32

typedef __attribute__((ext_vector_type(8)))  short bf16x8;
typedef __attribute__((ext_vector_type(16))) float f32x16;

__device__ __forceinline__ short f2bf(float f) {
    __hip_bfloat16 h = __float2bfloat16(f);
    return *reinterpret_cast<short*>(&h);
}

// ---------------- wide kernel: spart[cb][b][d] = sum of 64 rows ----------------
__global__ __launch_bounds__(256) void ksum(const float* __restrict__ u,
                                            float* __restrict__ spart) {
    int b = blockIdx.y, cb = blockIdx.x;        // cb: 0..31, 64 rows each
    int tid = threadIdx.x, cg = tid & 15, rr = tid >> 4;
    const float4* up = reinterpret_cast<const float4*>(
        u + ((size_t)b * NN + (size_t)cb * 64 + rr) * DD) + cg;
    float4 a = {0.f, 0.f, 0.f, 0.f};
    #pragma unroll
    for (int k = 0; k < 4; ++k) {
        float4 v = up[(size_t)k * 16 * (DD / 4)];
        a.x += v.x; a.y += v.y; a.z += v.z; a.w += v.w;
    }
    __shared__ float4 red[16][16];
    red[rr][cg] = a;
    __syncthreads();
    if (rr == 0) {
        float4 s = red[0][cg];
        #pragma unroll
        for (int r = 1; r < 16; ++r) {
            s.x += red[r][cg].x; s.y += red[r][cg].y;
            s.z += red[r][cg].z; s.w += red[r][cg].w;
        }
        reinterpret_cast<float4*>(spart + ((size_t)cb * BB + b) * DD)[cg] = s;
    }
}

// ---------------- fused kernel: 64 blocks x 512 threads ----------------
__global__ __launch_bounds__(512) void kf(const float* __restrict__ u,
                                          const float* __restrict__ W,
                                          const float* __restrict__ spart,
                                          float* __restrict__ out) {
    int b = blockIdx.x;
    int tid = threadIdx.x;
    int wv = tid >> 6;                  // wave 0..7, owns 256 rows
    int l = tid & 63, h = l >> 5, ln = l & 31;
    int ii = tid >> 4, jj0 = tid & 15;

    __shared__ unsigned short ush[8][2048];   // 32 KB per-wave u tile, bf16 hi
    __shared__ float cslab[8][II * 33];       // 33.8 KB per-wave c[n][i]
    __shared__ float tlds[II][65];            // 8.3 KB
    __shared__ float wlds[II][68];            // 8.7 KB
    __shared__ float ssum[DD];
    __shared__ float osh[II][16];

    const float* ubase = u + (size_t)b * NN * DD;

    // ---- phase B: s from spart, o0, l2norm, w~ ----
    if (tid < DD) {
        float a = 0.f;
        #pragma unroll
        for (int cb = 0; cb < 32; ++cb)
            a += spart[((size_t)cb * BB + b) * DD + tid];
        ssum[tid] = a;
    }
    for (int k = tid; k < II * 65; k += 512) (&tlds[0][0])[k] = 0.f;
    __syncthreads();
    {
        float o = 0.f;
        #pragma unroll 8
        for (int d = 0; d < DD; ++d) o += ssum[d] * W[d * 512 + ii * 16 + jj0];
        o *= (1.0f / 32.0f);
        float ss = o * o;
        #pragma unroll
        for (int off = 8; off >= 1; off >>= 1) ss += __shfl_xor(ss, off, 16);
        osh[ii][jj0] = o / sqrtf(fmaxf(ss, 1e-12f));
    }
    __syncthreads();
    #pragma unroll
    for (int k = 0; k < 4; ++k) {
        int d = jj0 + 16 * k;
        float acc = 0.f;
        #pragma unroll
        for (int j2 = 0; j2 < 16; ++j2)
            acc += W[d * 512 + ii * 16 + j2] * osh[ii][j2];
        wlds[ii][d] = acc;
    }
    __syncthreads();

    // ---- routing iterations ----
    for (int it = 0; it < 2; ++it) {
        bf16x8 Aw[4];
        #pragma unroll
        for (int kt = 0; kt < 4; ++kt) {
            const float* p = &wlds[ln][kt * 16 + h * 8];
            #pragma unroll
            for (int e2 = 0; e2 < 8; ++e2) Aw[kt][e2] = f2bf(p[e2]);
        }
        f32x16 G0, G1;
        #pragma unroll
        for (int r = 0; r < 16; ++r) { G0[r] = 0.f; G1[r] = 0.f; }

        for (int tt = 0; tt < 8; ++tt) {
            int n0 = wv * 256 + tt * 32;
            // load row n0+ln (8 float4), cvt hi-only, stage swizzled slab
            bf16x8 Bh[4];
            #pragma unroll
            for (int kt = 0; kt < 4; ++kt) {
                const float4* p = reinterpret_cast<const float4*>(
                    ubase + (size_t)(n0 + ln) * DD + kt * 16 + h * 8);
                float4 v0 = p[0], v1 = p[1];
                Bh[kt][0] = f2bf(v0.x); Bh[kt][1] = f2bf(v0.y);
                Bh[kt][2] = f2bf(v0.z); Bh[kt][3] = f2bf(v0.w);
                Bh[kt][4] = f2bf(v1.x); Bh[kt][5] = f2bf(v1.y);
                Bh[kt][6] = f2bf(v1.z); Bh[kt][7] = f2bf(v1.w);
                int d0 = kt * 16 + h * 8;
                int idx = ln * 64 + (d0 ^ ((ln & 7) << 3));
                *reinterpret_cast<bf16x8*>(&ush[wv][idx]) = Bh[kt];
            }
            // phase 1: logits C[i][n], col = ln  -> cheap lane-local softmax
            f32x16 S;
            #pragma unroll
            for (int r = 0; r < 16; ++r) S[r] = 0.f;
            #pragma unroll
            for (int kt = 0; kt < 4; ++kt)
                S = __builtin_amdgcn_mfma_f32_32x32x16_bf16(Aw[kt], Bh[kt], S, 0, 0, 0);
            float m = S[0];
            #pragma unroll
            for (int r = 1; r < 16; ++r) m = fmaxf(m, S[r]);
            m = fmaxf(m, __shfl_xor(m, 32));
            float sum = 0.f, e[16];
            #pragma unroll
            for (int r = 0; r < 16; ++r) { e[r] = __expf(S[r] - m); sum += e[r]; }
            sum += __shfl_xor(sum, 32);
            float inv = 1.f / sum;
            #pragma unroll
            for (int r = 0; r < 16; ++r) {
                int irow = (r & 3) + 8 * (r >> 2) + 4 * h;
                cslab[wv][ln * 33 + irow] = e[r] * inv;   // c[n=ln][i]
            }
            // phase 2: G += mfma(c^T, u), hi-only (4 MFMA/tile)
            #pragma unroll
            for (int t2 = 0; t2 < 2; ++t2) {
                bf16x8 Ah;
                #pragma unroll
                for (int qq = 0; qq < 8; ++qq)
                    Ah[qq] = f2bf(cslab[wv][(t2 * 16 + h * 8 + qq) * 33 + ln]);
                #pragma unroll
                for (int Nt = 0; Nt < 2; ++Nt) {
                    bf16x8 B2h;
                    #pragma unroll
                    for (int qq = 0; qq < 8; ++qq) {
                        int row = t2 * 16 + h * 8 + qq;
                        int idx = row * 64 + ((Nt * 32 + ln) ^ ((row & 7) << 3));
                        B2h[qq] = (short)ush[wv][idx];
                    }
                    if (Nt == 0)
                        G0 = __builtin_amdgcn_mfma_f32_32x32x16_bf16(Ah, B2h, G0, 0, 0, 0);
                    else
                        G1 = __builtin_amdgcn_mfma_f32_32x32x16_bf16(Ah, B2h, G1, 0, 0, 0);
                }
            }
        }

        // cross-wave LDS reduce
        #pragma unroll
        for (int r = 0; r < 16; ++r) {
            int irow = (r & 3) + 8 * (r >> 2) + 4 * h;
            atomicAdd(&tlds[irow][ln],      G0[r]);
            atomicAdd(&tlds[irow][32 + ln], G1[r]);
        }
        __syncthreads();

        // epilogue: o = t @ W_i, l2norm->w~ or squash->out
        float o = 0.f;
        #pragma unroll 8
        for (int d = 0; d < DD; ++d) o += tlds[ii][d] * W[d * 512 + ii * 16 + jj0];
        float ss = o * o;
        #pragma unroll
        for (int off = 8; off >= 1; off >>= 1) ss += __shfl_xor(ss, off, 16);

        if (it == 0) {
            float ov = o / sqrtf(fmaxf(ss, 1e-12f));     // tf l2_normalize
            __syncthreads();
            osh[ii][jj0] = ov;
            __syncthreads();
            #pragma unroll
            for (int k = 0; k < 4; ++k) {
                int d = jj0 + 16 * k;
                float acc = 0.f;
                #pragma unroll
                for (int j2 = 0; j2 < 16; ++j2)
                    acc += W[d * 512 + ii * 16 + j2] * osh[ii][j2];
                wlds[ii][d] = acc;
            }
            for (int k = tid; k < II * 65; k += 512) (&tlds[0][0])[k] = 0.f;
            __syncthreads();
        } else {
            float s2 = ss + 1e-7f;                       // K.epsilon
            float scale = sqrtf(s2) / (0.5f + s2);       // squash
            out[(size_t)b * 512 + tid] = scale * o;
        }
    }
}

extern "C" void kernel_launch(void* const* d_in, const int* in_sizes, int n_in,
                              void* d_out, int out_size, void* d_ws, size_t ws_size,
                              hipStream_t stream) {
    const float* u = (const float*)d_in[0];     // (64, 2048, 64)
    const float* W = (const float*)d_in[1];     // (1, 64, 512)
    float* out = (float*)d_out;                 // (64, 32, 16)
    float* ws = (float*)d_ws;

    float* spart = ws;                          // 131072 floats (512 KB)

    ksum<<<dim3(32, BB), 256, 0, stream>>>(u, spart);   // wide: all CUs
    kf<<<BB, 512, 0, stream>>>(u, W, spart, out);       // fused routing
}